// Round 4
// baseline (442.419 us; speedup 1.0000x reference)
//
#include <hip/hip_runtime.h>
#include <math.h>

#define HD 128      // hidden dim (= F_IN)
#define ED 16       // edge feat dim
#define NG 64       // num graphs
#define NC 10       // num classes

typedef short bf16x8 __attribute__((ext_vector_type(8)));
typedef float f32x4 __attribute__((ext_vector_type(4)));

__device__ __forceinline__ unsigned short f2b(float x){
  unsigned u = __float_as_uint(x);
  unsigned r = (u + 0x7fffu + ((u >> 16) & 1u)) >> 16;
  return (unsigned short)r;
}
__device__ __forceinline__ float blo(unsigned p){ return __uint_as_float(p << 16); }
__device__ __forceinline__ float bhi(unsigned p){ return __uint_as_float(p & 0xffff0000u); }
__device__ __forceinline__ float bperm_f(int idx, float v){
  return __int_as_float(__builtin_amdgcn_ds_bpermute(idx<<2, __float_as_int(v)));
}
__device__ __forceinline__ int bperm_i(int idx, int v){
  return __builtin_amdgcn_ds_bpermute(idx<<2, v);
}

// ---------------- CSR build ----------------
// hist ALSO captures each edge's rank within its dst bucket (the atomic's
// return value, previously discarded) -> k_scatterq needs no atomic at all.
__global__ void k_hist(const int* __restrict__ dst, int* __restrict__ deg,
                       int* __restrict__ rank, int E){
  int e4 = (blockIdx.x*blockDim.x + threadIdx.x)*4;
  if(e4+3 < E){
    int4 d = *(const int4*)&dst[e4];
    int4 r;
    r.x = atomicAdd(&deg[d.x], 1);
    r.y = atomicAdd(&deg[d.y], 1);
    r.z = atomicAdd(&deg[d.z], 1);
    r.w = atomicAdd(&deg[d.w], 1);
    *(int4*)&rank[e4] = r;
  } else {
    for(int k=0;k<4;k++) if(e4+k<E) rank[e4+k] = atomicAdd(&deg[dst[e4+k]], 1);
  }
}

__global__ __launch_bounds__(64) void k_bsum(const int* __restrict__ deg, int* __restrict__ bsum, int N){
  int b = blockIdx.x, t = threadIdx.x;
  int i = b*256 + t*4;
  int s = 0;
  if(i+3 < N){ int4 v = *(const int4*)&deg[i]; s = v.x+v.y+v.z+v.w; }
  else { for(int k=0;k<4;k++) if(i+k<N) s += deg[i+k]; }
  #pragma unroll
  for(int o=32;o;o>>=1) s += __shfl_xor(s,o);
  if(t==0) bsum[b] = s;
}

__global__ __launch_bounds__(1024) void k_bscan(const int* __restrict__ bsum, int* __restrict__ bbase,
                                                int* __restrict__ offs, int N, int nb){
  __shared__ int sh[1024];
  int t = threadIdx.x;
  int v = (t < nb) ? bsum[t] : 0;
  sh[t] = v; __syncthreads();
  for(int o=1;o<1024;o<<=1){ int u = (t>=o)?sh[t-o]:0; __syncthreads(); sh[t]+=u; __syncthreads(); }
  if(t < nb) bbase[t] = sh[t] - v;
  if(t == 1023) offs[N] = sh[1023];
}

__global__ __launch_bounds__(256) void k_bprop(const int* __restrict__ deg, const int* __restrict__ bbase,
                                               int* __restrict__ offs, int N){
  __shared__ int sh[256];
  int b = blockIdx.x, t = threadIdx.x;
  int i = b*256 + t;
  int v = (i<N) ? deg[i] : 0;
  sh[t] = v; __syncthreads();
  for(int o=1;o<256;o<<=1){ int u = (t>=o)?sh[t-o]:0; __syncthreads(); sh[t]+=u; __syncthreads(); }
  if(i<N){ offs[i] = bbase[b] + sh[t] - v; }
}

// ---------------- scatter + fused edge dots: ONE 8B record per edge ----------------
// rec[p] (uint2): x = q1b | q2b<<16 ; y = src(u16) | q3b<<16   (requires N <= 65536)
// 4 lanes cooperate per edge (coalesced efeat loads). p = offs[dst] + rank[e]
// is computed from coalesced loads -> NO atomic, stores pipeline freely.
__global__ __launch_bounds__(256) void k_scatterq(const int* __restrict__ src, const int* __restrict__ dst,
                           const int* __restrict__ rank,
                           const float* __restrict__ ef,
                           const float* __restrict__ a1e, const float* __restrict__ a2e,
                           const float* __restrict__ a3e,
                           const int* __restrict__ offs, uint2* __restrict__ rec, int E){
  int t = blockIdx.x*256 + threadIdx.x;
  int e = t >> 2;
  int sub = t & 3;
  if(e >= E) return;
  float4 f  = *(const float4*)&ef[(size_t)e*ED + sub*4];
  float4 A1 = *(const float4*)&a1e[sub*4];
  float4 A2 = *(const float4*)&a2e[sub*4];
  float4 A3 = *(const float4*)&a3e[sub*4];
  float q1 = fmaf(f.x,A1.x, fmaf(f.y,A1.y, fmaf(f.z,A1.z, f.w*A1.w)));
  float q2 = fmaf(f.x,A2.x, fmaf(f.y,A2.y, fmaf(f.z,A2.z, f.w*A2.w)));
  float q3 = fmaf(f.x,A3.x, fmaf(f.y,A3.y, fmaf(f.z,A3.z, f.w*A3.w)));
  q1 += __shfl_xor(q1,1); q1 += __shfl_xor(q1,2);
  q2 += __shfl_xor(q2,1); q2 += __shfl_xor(q2,2);
  q3 += __shfl_xor(q3,1); q3 += __shfl_xor(q3,2);
  if(sub == 0){
    int d = dst[e];
    int p = offs[d] + rank[e];
    uint2 A;
    A.x = (unsigned)f2b(q1) | ((unsigned)f2b(q2) << 16);
    A.y = (unsigned)src[e] | ((unsigned)f2b(q3) << 16);
    rec[p] = A;
  }
}

// ---------------- merged setup: x cast | W swizzle | graph counts ----------------
__global__ __launch_bounds__(256) void k_setup(const float* __restrict__ x, unsigned short* __restrict__ xb,
                        const float* __restrict__ W1, const float* __restrict__ W2,
                        const float* __restrict__ W3, unsigned short* __restrict__ Wb,
                        const int* __restrict__ gid, float* __restrict__ cnt,
                        int N, int ncast){
  int b = blockIdx.x;
  if(b < ncast){
    int i = (b*256 + threadIdx.x)*8;
    if(i >= N*HD) return;
    float4 v0 = *(const float4*)&x[i];
    float4 v1 = *(const float4*)&x[i+4];
    uint4 o;
    o.x = f2b(v0.x) | ((unsigned)f2b(v0.y)<<16);
    o.y = f2b(v0.z) | ((unsigned)f2b(v0.w)<<16);
    o.z = f2b(v1.x) | ((unsigned)f2b(v1.y)<<16);
    o.w = f2b(v1.z) | ((unsigned)f2b(v1.w)<<16);
    *(uint4*)&xb[i] = o;
  } else if(b < ncast + 24){
    int idx = (b - ncast)*256 + threadIdx.x;    // 3 * 2048
    if(idx >= 3*2048) return;
    int layer = idx >> 11;
    int r = idx & 2047;
    const float* W = (layer==0)?W1:((layer==1)?W2:W3);
    int lane = r & 63, tile = r >> 6;
    int kt = tile >> 3, nt = tile & 7;
    int qq = lane >> 4, cc = lane & 15;
    int kbase = kt*32 + qq*8;
    int col = nt*16 + cc;
    unsigned short tmp[8];
    #pragma unroll
    for(int j=0;j<8;j++) tmp[j] = f2b(W[(size_t)(kbase+j)*HD + col]);
    uint4 o;
    o.x = tmp[0]|((unsigned)tmp[1]<<16); o.y = tmp[2]|((unsigned)tmp[3]<<16);
    o.z = tmp[4]|((unsigned)tmp[5]<<16); o.w = tmp[6]|((unsigned)tmp[7]<<16);
    *(uint4*)&Wb[(size_t)idx*8] = o;
  } else {
    int g = threadIdx.x;
    if(g >= NG) return;
    int lo=0, hi=N;
    while(lo<hi){ int mid=(lo+hi)>>1; if(gid[mid] < g) lo=mid+1; else hi=mid; }
    int start = lo; lo = start; hi = N;
    while(lo<hi){ int mid=(lo+hi)>>1; if(gid[mid] < g+1) lo=mid+1; else hi=mid; }
    cnt[g] = (float)(lo - start);
  }
}

// ---------------- MFMA GEMM: Zb[M x 128](bf16) = Ab @ W, fused pdots ----------------
__global__ __launch_bounds__(256) void k_gemm_mfma(
    const unsigned short* __restrict__ Ab,
    const unsigned short* __restrict__ Wb,
    unsigned short* __restrict__ Zb,
    const float* __restrict__ avec,
    float* __restrict__ ps, float* __restrict__ pd, int M)
{
  int tid = threadIdx.x;
  int w = tid >> 6, lane = tid & 63;
  int q = lane >> 4, c = lane & 15;
  int rowbase = blockIdx.x*128 + w*32;
  f32x4 acc[2][8];
  #pragma unroll
  for(int t=0;t<2;t++)
    #pragma unroll
    for(int n=0;n<8;n++) acc[t][n] = (f32x4){0.f,0.f,0.f,0.f};

  int r0 = rowbase + c;      if(r0 > M-1) r0 = M-1;
  int r1 = rowbase + 16 + c; if(r1 > M-1) r1 = M-1;
  #pragma unroll
  for(int kt=0; kt<4; kt++){
    int ko = kt*32 + q*8;
    bf16x8 a0 = __builtin_bit_cast(bf16x8, *(const uint4*)&Ab[(size_t)r0*HD + ko]);
    bf16x8 a1 = __builtin_bit_cast(bf16x8, *(const uint4*)&Ab[(size_t)r1*HD + ko]);
    #pragma unroll
    for(int n=0;n<8;n++){
      bf16x8 b = __builtin_bit_cast(bf16x8, *(const uint4*)&Wb[(((size_t)(kt*8+n))*64 + lane)*8]);
      acc[0][n] = __builtin_amdgcn_mfma_f32_16x16x32_bf16(a0, b, acc[0][n], 0,0,0);
      acc[1][n] = __builtin_amdgcn_mfma_f32_16x16x32_bf16(a1, b, acc[1][n], 0,0,0);
    }
  }
  float asv[8], adv[8];
  #pragma unroll
  for(int n=0;n<8;n++){ asv[n] = avec[n*16+c]; adv[n] = avec[HD + n*16+c]; }
  #pragma unroll
  for(int t=0;t<2;t++){
    #pragma unroll
    for(int r=0;r<4;r++){
      int grow = rowbase + t*16 + 4*q + r;
      bool ok = grow < M;
      #pragma unroll
      for(int n=0;n<8;n++){
        if(ok) Zb[(size_t)grow*HD + n*16 + c] = f2b(acc[t][n][r]);
      }
      float pp = 0.f, dd = 0.f;
      #pragma unroll
      for(int n=0;n<8;n++){ pp = fmaf(acc[t][n][r], asv[n], pp); dd = fmaf(acc[t][n][r], adv[n], dd); }
      #pragma unroll
      for(int o=1;o<16;o<<=1){ pp += __shfl_xor(pp,o); dd += __shfl_xor(dd,o); }
      if(ok && c==0){ ps[grow] = pp; pd[grow] = dd; }
    }
  }
}

// ---------------- fused logits + softmax + aggregate + relu + h(bf16) + att ----------------
// TWO nodes per wave (A = 2*pair, B = 2*pair+1): their dependent chains
// (rec -> ps gather -> exp -> reduce -> bperm -> row gather -> FMA) are
// interleaved phase-by-phase so the two latency chains overlap in one wave.
// Inner 16-edge group structure identical to the proven 43us version.
#define FMAS(ACC, W0,W1,W2,W3, P0,P1,P2,P3) \
  ACC[0]=fmaf(W0,blo(P0.x),ACC[0]); ACC[1]=fmaf(W0,bhi(P0.x),ACC[1]); \
  ACC[2]=fmaf(W0,blo(P0.y),ACC[2]); ACC[3]=fmaf(W0,bhi(P0.y),ACC[3]); \
  ACC[4]=fmaf(W0,blo(P0.z),ACC[4]); ACC[5]=fmaf(W0,bhi(P0.z),ACC[5]); \
  ACC[6]=fmaf(W0,blo(P0.w),ACC[6]); ACC[7]=fmaf(W0,bhi(P0.w),ACC[7]); \
  ACC[0]=fmaf(W1,blo(P1.x),ACC[0]); ACC[1]=fmaf(W1,bhi(P1.x),ACC[1]); \
  ACC[2]=fmaf(W1,blo(P1.y),ACC[2]); ACC[3]=fmaf(W1,bhi(P1.y),ACC[3]); \
  ACC[4]=fmaf(W1,blo(P1.z),ACC[4]); ACC[5]=fmaf(W1,bhi(P1.z),ACC[5]); \
  ACC[6]=fmaf(W1,blo(P1.w),ACC[6]); ACC[7]=fmaf(W1,bhi(P1.w),ACC[7]); \
  ACC[0]=fmaf(W2,blo(P2.x),ACC[0]); ACC[1]=fmaf(W2,bhi(P2.x),ACC[1]); \
  ACC[2]=fmaf(W2,blo(P2.y),ACC[2]); ACC[3]=fmaf(W2,bhi(P2.y),ACC[3]); \
  ACC[4]=fmaf(W2,blo(P2.z),ACC[4]); ACC[5]=fmaf(W2,bhi(P2.z),ACC[5]); \
  ACC[6]=fmaf(W2,blo(P2.w),ACC[6]); ACC[7]=fmaf(W2,bhi(P2.w),ACC[7]); \
  ACC[0]=fmaf(W3,blo(P3.x),ACC[0]); ACC[1]=fmaf(W3,bhi(P3.x),ACC[1]); \
  ACC[2]=fmaf(W3,blo(P3.y),ACC[2]); ACC[3]=fmaf(W3,bhi(P3.y),ACC[3]); \
  ACC[4]=fmaf(W3,blo(P3.z),ACC[4]); ACC[5]=fmaf(W3,bhi(P3.z),ACC[5]); \
  ACC[6]=fmaf(W3,blo(P3.w),ACC[6]); ACC[7]=fmaf(W3,bhi(P3.w),ACC[7]);

__global__ __launch_bounds__(256) void k_agg2(const uint4* __restrict__ zb4,
                                              const int* __restrict__ offs,
                                              const uint2* __restrict__ rec,
                                              const float* __restrict__ ps,
                                              const float* __restrict__ pd,
                                              int layer,
                                              unsigned* __restrict__ hbu,
                                              float* __restrict__ att,
                                              const float* __restrict__ watt,
                                              const float* __restrict__ batt, int N){
  int lane = threadIdx.x & 63;
  int widA = (blockIdx.x*4 + (threadIdx.x>>6))*2;
  int widB = widA + 1;
  if(widA >= N) return;
  bool hasB = (widB < N);
  int q = lane >> 4, c = lane & 15;
  int d0a = offs[widA];
  int d1a = offs[widA+1];
  int d1b = hasB ? offs[widB+1] : d1a;
  int d0b = d1a;                        // CSR: bucket B starts where A ends
  float pdvA = pd[widA];
  float pdvB = hasB ? pd[widB] : 0.f;
  float accA[8], accB[8];
  #pragma unroll
  for(int i=0;i<8;i++){ accA[i]=0.f; accB[i]=0.f; }
  float ssumA = 0.f, ssumB = 0.f;
  int t0a = d0a, t0b = d0b;

  while(t0a < d1a || t0b < d1b){
    int remA = d1a - t0a; remA = remA < 0 ? 0 : (remA > 64 ? 64 : remA);
    int remB = d1b - t0b; remB = remB < 0 ? 0 : (remB > 64 ? 64 : remB);
    int ja  = t0a + lane;
    int jb2 = t0b + lane;
    // ---- phase 1: per-lane edge weight, both nodes (chains overlap) ----
    float wAv = 0.f; int uA = 0;
    if(ja < d1a){
      uint2 R = rec[ja];
      uA = (int)(R.y & 0xffffu);
      unsigned qv = (layer==0) ? (R.x & 0xffffu) : (layer==1 ? (R.x >> 16) : (R.y >> 16));
      float l = ps[uA] + pdvA + __uint_as_float(qv << 16);
      l = (l >= 0.f) ? l : 0.2f*l;
      wAv = __expf(l);
    }
    float wBv = 0.f; int uB = 0;
    if(jb2 < d1b){
      uint2 R = rec[jb2];
      uB = (int)(R.y & 0xffffu);
      unsigned qv = (layer==0) ? (R.x & 0xffffu) : (layer==1 ? (R.x >> 16) : (R.y >> 16));
      float l = ps[uB] + pdvB + __uint_as_float(qv << 16);
      l = (l >= 0.f) ? l : 0.2f*l;
      wBv = __expf(l);
    }
    float wsA = wAv, wsB = wBv;
    #pragma unroll
    for(int o=32;o;o>>=1){ wsA += __shfl_xor(wsA,o); wsB += __shfl_xor(wsB,o); }
    ssumA += wsA; ssumB += wsB;
    // ---- phase 2: 16 edges/group per node; issue both gather clusters, then FMA ----
    int gmax = remA > remB ? remA : remB;
    for(int jb=0; jb<gmax; jb+=16){
      bool doA = jb < remA, doB = jb < remB;     // wave-uniform
      float aw0,aw1,aw2,aw3, bw0,bw1,bw2,bw3;
      uint4 AP0,AP1,AP2,AP3, BP0,BP1,BP2,BP3;
      if(doA){
        aw0 = bperm_f(jb+q,    wAv);  int u0 = bperm_i(jb+q,    uA);
        aw1 = bperm_f(jb+4+q,  wAv);  int u1 = bperm_i(jb+4+q,  uA);
        aw2 = bperm_f(jb+8+q,  wAv);  int u2 = bperm_i(jb+8+q,  uA);
        aw3 = bperm_f(jb+12+q, wAv);  int u3 = bperm_i(jb+12+q, uA);
        AP0 = zb4[(size_t)u0*16 + c];
        AP1 = zb4[(size_t)u1*16 + c];
        AP2 = zb4[(size_t)u2*16 + c];
        AP3 = zb4[(size_t)u3*16 + c];
      }
      if(doB){
        bw0 = bperm_f(jb+q,    wBv);  int u0 = bperm_i(jb+q,    uB);
        bw1 = bperm_f(jb+4+q,  wBv);  int u1 = bperm_i(jb+4+q,  uB);
        bw2 = bperm_f(jb+8+q,  wBv);  int u2 = bperm_i(jb+8+q,  uB);
        bw3 = bperm_f(jb+12+q, wBv);  int u3 = bperm_i(jb+12+q, uB);
        BP0 = zb4[(size_t)u0*16 + c];
        BP1 = zb4[(size_t)u1*16 + c];
        BP2 = zb4[(size_t)u2*16 + c];
        BP3 = zb4[(size_t)u3*16 + c];
      }
      if(doA){ FMAS(accA, aw0,aw1,aw2,aw3, AP0,AP1,AP2,AP3) }
      if(doB){ FMAS(accB, bw0,bw1,bw2,bw3, BP0,BP1,BP2,BP3) }
    }
    t0a += 64; t0b += 64;
  }

  // ---- epilogue (A, then B) ----
  float4 w0v = *(const float4*)&watt[c*8];
  float4 w1v = *(const float4*)&watt[c*8+4];
  float bat = batt[0];

  #pragma unroll
  for(int i=0;i<8;i++){ accA[i] += __shfl_xor(accA[i],16); accA[i] += __shfl_xor(accA[i],32); }
  float invA = (d1a > d0a) ? 1.0f/ssumA : 0.0f;
  #pragma unroll
  for(int i=0;i<8;i++) accA[i] = fmaxf(accA[i]*invA, 0.f);
  hbu[(size_t)widA*64 + c*4 + q] = (unsigned)f2b(accA[2*q]) | ((unsigned)f2b(accA[2*q+1])<<16);
  float tA = accA[0]*w0v.x + accA[1]*w0v.y + accA[2]*w0v.z + accA[3]*w0v.w
           + accA[4]*w1v.x + accA[5]*w1v.y + accA[6]*w1v.z + accA[7]*w1v.w;
  #pragma unroll
  for(int o=1;o<16;o<<=1) tA += __shfl_xor(tA,o);
  tA += bat;
  float lrA = (tA >= 0.f) ? tA : 0.01f*tA;
  if(lane==0) att[widA] = __expf(lrA);

  if(hasB){
    #pragma unroll
    for(int i=0;i<8;i++){ accB[i] += __shfl_xor(accB[i],16); accB[i] += __shfl_xor(accB[i],32); }
    float invB = (d1b > d0b) ? 1.0f/ssumB : 0.0f;
    #pragma unroll
    for(int i=0;i<8;i++) accB[i] = fmaxf(accB[i]*invB, 0.f);
    hbu[(size_t)widB*64 + c*4 + q] = (unsigned)f2b(accB[2*q]) | ((unsigned)f2b(accB[2*q+1])<<16);
    float tB = accB[0]*w0v.x + accB[1]*w0v.y + accB[2]*w0v.z + accB[3]*w0v.w
             + accB[4]*w1v.x + accB[5]*w1v.y + accB[6]*w1v.z + accB[7]*w1v.w;
    #pragma unroll
    for(int o=1;o<16;o<<=1) tB += __shfl_xor(tB,o);
    tB += bat;
    float lrB = (tB >= 0.f) ? tB : 0.01f*tB;
    if(lane==0) att[widB] = __expf(lrB);
  }
}

// ---------------- readout: hg[g] += att[v] * h[v] ----------------
#define RCH 16
__global__ __launch_bounds__(64) void k_readout(const unsigned* __restrict__ hbu,
                                                const float* __restrict__ att,
                                                const int* __restrict__ gid,
                                                float* __restrict__ hg, int N){
  int g = blockIdx.x / RCH;
  int chunk = blockIdx.x % RCH;
  int t = threadIdx.x;
  int lo=0, hi=N;
  while(lo<hi){ int mid=(lo+hi)>>1; if(gid[mid] < g) lo=mid+1; else hi=mid; }
  int start = lo; lo = start; hi = N;
  while(lo<hi){ int mid=(lo+hi)>>1; if(gid[mid] < g+1) lo=mid+1; else hi=mid; }
  int end = lo;
  int len = end - start;
  int c0 = start + (int)(((long long)len * chunk) / RCH);
  int c1 = start + (int)(((long long)len * (chunk+1)) / RCH);
  float acc0 = 0.f, acc1 = 0.f;
  for(int v=c0; v<c1; v++){
    unsigned P = hbu[(size_t)v*64 + t];
    float a = att[v];
    acc0 = fmaf(a, blo(P), acc0);
    acc1 = fmaf(a, bhi(P), acc1);
  }
  atomicAdd(&hg[g*HD + 2*t],     acc0);
  atomicAdd(&hg[g*HD + 2*t + 1], acc1);
}

// ---------------- final classifier + log_softmax (block per graph) ----------------
__global__ __launch_bounds__(384) void k_final(const float* __restrict__ hg,
                                               const float* __restrict__ cnt,
                                               const float* __restrict__ Wc,
                                               const float* __restrict__ bc,
                                               float* __restrict__ out){
  int g = blockIdx.x;
  int t = threadIdx.x;
  __shared__ float red[6];
  __shared__ float yv[NC];
  float invc = 1.f / fmaxf(cnt[g], 1.f);
  int part = t >> 7;
  int f = t & 127;
  float v = hg[(size_t)part*NG*HD + g*HD + f] * invc;
  for(int c=0; c<NC; c++){
    float p = v * Wc[(size_t)t*NC + c];
    #pragma unroll
    for(int o=32;o;o>>=1) p += __shfl_xor(p,o);
    if((t&63)==0) red[t>>6] = p;
    __syncthreads();
    if(t==0) yv[c] = bc[c] + red[0]+red[1]+red[2]+red[3]+red[4]+red[5];
    __syncthreads();
  }
  if(t==0){
    float mx = -INFINITY;
    #pragma unroll
    for(int c=0;c<NC;c++) mx = fmaxf(mx, yv[c]);
    float s = 0.f;
    #pragma unroll
    for(int c=0;c<NC;c++) s += __expf(yv[c] - mx);
    float ls = logf(s);
    #pragma unroll
    for(int c=0;c<NC;c++) out[g*NC + c] = yv[c] - mx - ls;
  }
}

// ---------------- host ----------------
extern "C" void kernel_launch(void* const* d_in, const int* in_sizes, int n_in,
                              void* d_out, int out_size, void* d_ws, size_t ws_size,
                              hipStream_t stream) {
  const float* x     = (const float*)d_in[0];
  const float* efeat = (const float*)d_in[1];
  const int*   src   = (const int*)d_in[2];
  const int*   dst   = (const int*)d_in[3];
  const int*   gid   = (const int*)d_in[4];
  const float* W1    = (const float*)d_in[5];
  const float* a1    = (const float*)d_in[6];
  const float* W2    = (const float*)d_in[7];
  const float* a2    = (const float*)d_in[8];
  const float* W3    = (const float*)d_in[9];
  const float* a3    = (const float*)d_in[10];
  const float* watt  = (const float*)d_in[11];
  const float* batt  = (const float*)d_in[12];
  const float* Wc    = (const float*)d_in[13];
  const float* bc    = (const float*)d_in[14];
  float* out = (float*)d_out;

  int N = in_sizes[4];
  int E = in_sizes[2];

  char* p = (char*)d_ws;
  auto alloc = [&](size_t bytes)->void*{
    void* r = (void*)p;
    p += (bytes + 255) & ~(size_t)255;
    return r;
  };
  unsigned short* Xb = (unsigned short*)alloc((size_t)N*HD*2);
  unsigned short* Hb = (unsigned short*)alloc((size_t)N*HD*2);
  unsigned short* Zb = (unsigned short*)alloc((size_t)N*HD*2);
  unsigned short* Wball = (unsigned short*)alloc((size_t)3*2048*8*2);
  float* ps      = (float*)alloc((size_t)N*4);
  float* pd      = (float*)alloc((size_t)N*4);
  float* att     = (float*)alloc((size_t)N*4);
  int*   deg     = (int*)  alloc((size_t)N*4);
  int*   offs    = (int*)  alloc((size_t)(N+1)*4);
  int*   rank    = (int*)  alloc((size_t)E*4);
  uint2* rec     = (uint2*)alloc((size_t)E*8);
  int*   bsum    = (int*)  alloc((size_t)1024*4);
  int*   bbase   = (int*)  alloc((size_t)1024*4);
  float* hg      = (float*)alloc((size_t)3*NG*HD*4);
  float* cnt     = (float*)alloc((size_t)NG*4);
  (void)ws_size; (void)n_in; (void)out_size;

  int nwblocks = (N + 7) / 8;     // 4 waves/block x 2 nodes/wave
  int nb = (N + 255) / 256;
  int ncast = (N*16 + 255) / 256;

  hipMemsetAsync(deg, 0, (size_t)N*4, stream);
  hipMemsetAsync(hg, 0, (size_t)3*NG*HD*4, stream);
  k_hist<<<(E/4 + 255)/256, 256, 0, stream>>>(dst, deg, rank, E);
  k_bsum<<<nb, 64, 0, stream>>>(deg, bsum, N);
  k_bscan<<<1, 1024, 0, stream>>>(bsum, bbase, offs, N, nb);
  k_bprop<<<nb, 256, 0, stream>>>(deg, bbase, offs, N);
  k_scatterq<<<(E*4 + 255)/256, 256, 0, stream>>>(src, dst, rank, efeat,
                                                  a1+2*HD, a2+2*HD, a3+2*HD,
                                                  offs, rec, E);
  k_setup<<<ncast + 25, 256, 0, stream>>>(x, Xb, W1, W2, W3, Wball, gid, cnt, N, ncast);

  const float* as[3] = {a1, a2, a3};
  for(int layer=0; layer<3; layer++){
    const unsigned short* Ab = (layer==0) ? Xb : Hb;
    k_gemm_mfma<<<(N+127)/128, 256, 0, stream>>>(Ab, Wball + (size_t)layer*2048*8, Zb,
                                                 as[layer], ps, pd, N);
    k_agg2<<<nwblocks, 256, 0, stream>>>((const uint4*)Zb, offs, rec, ps, pd, layer,
                                         (unsigned*)Hb, att, watt, batt, N);
    k_readout<<<NG*RCH, 64, 0, stream>>>((const unsigned*)Hb, att, gid,
                                         hg + (size_t)layer*NG*HD, N);
  }
  k_final<<<NG, 384, 0, stream>>>(hg, cnt, Wc, bc, out);
}

// Round 5
// 415.069 us; speedup vs baseline: 1.0659x; 1.0659x over previous
//
#include <hip/hip_runtime.h>
#include <math.h>

#define HD 128      // hidden dim (= F_IN)
#define ED 16       // edge feat dim
#define NG 64       // num graphs
#define NC 10       // num classes

typedef short bf16x8 __attribute__((ext_vector_type(8)));
typedef float f32x4 __attribute__((ext_vector_type(4)));

__device__ __forceinline__ unsigned short f2b(float x){
  unsigned u = __float_as_uint(x);
  unsigned r = (u + 0x7fffu + ((u >> 16) & 1u)) >> 16;
  return (unsigned short)r;
}
__device__ __forceinline__ float blo(unsigned p){ return __uint_as_float(p << 16); }
__device__ __forceinline__ float bhi(unsigned p){ return __uint_as_float(p & 0xffff0000u); }
__device__ __forceinline__ float bperm_f(int idx, float v){
  return __int_as_float(__builtin_amdgcn_ds_bpermute(idx<<2, __float_as_int(v)));
}
__device__ __forceinline__ int bperm_i(int idx, int v){
  return __builtin_amdgcn_ds_bpermute(idx<<2, v);
}

// ================= merged pre-kernel: hist | x cast | W swizzle | cnt | hg zero =================
// All parts are mutually independent -> one dispatch, latency-bound hist
// overlaps with streaming casts.
__global__ __launch_bounds__(256) void k_pre(
    const int* __restrict__ dst, int* __restrict__ deg, int* __restrict__ rank, int E, int NH,
    const float* __restrict__ x, unsigned short* __restrict__ xb,
    const float* __restrict__ W1, const float* __restrict__ W2, const float* __restrict__ W3,
    unsigned short* __restrict__ Wb,
    const int* __restrict__ gid, float* __restrict__ cnt,
    float* __restrict__ hg,
    int N, int ncast){
  int b = blockIdx.x;
  if(b < NH){
    // ---- hist + rank capture ----
    int e4 = (b*256 + threadIdx.x)*4;
    if(e4+3 < E){
      int4 d = *(const int4*)&dst[e4];
      int4 r;
      r.x = atomicAdd(&deg[d.x], 1);
      r.y = atomicAdd(&deg[d.y], 1);
      r.z = atomicAdd(&deg[d.z], 1);
      r.w = atomicAdd(&deg[d.w], 1);
      *(int4*)&rank[e4] = r;
    } else {
      for(int k=0;k<4;k++) if(e4+k<E) rank[e4+k] = atomicAdd(&deg[dst[e4+k]], 1);
    }
    return;
  }
  b -= NH;
  if(b < ncast){
    // ---- x -> bf16 ----
    int i = (b*256 + threadIdx.x)*8;
    if(i >= N*HD) return;
    float4 v0 = *(const float4*)&x[i];
    float4 v1 = *(const float4*)&x[i+4];
    uint4 o;
    o.x = f2b(v0.x) | ((unsigned)f2b(v0.y)<<16);
    o.y = f2b(v0.z) | ((unsigned)f2b(v0.w)<<16);
    o.z = f2b(v1.x) | ((unsigned)f2b(v1.y)<<16);
    o.w = f2b(v1.z) | ((unsigned)f2b(v1.w)<<16);
    *(uint4*)&xb[i] = o;
    return;
  }
  b -= ncast;
  if(b < 24){
    // ---- W swizzle (3 layers x 2048 rows) ----
    int idx = b*256 + threadIdx.x;
    if(idx >= 3*2048) return;
    int layer = idx >> 11;
    int r = idx & 2047;
    const float* W = (layer==0)?W1:((layer==1)?W2:W3);
    int lane = r & 63, tile = r >> 6;
    int kt = tile >> 3, nt = tile & 7;
    int qq = lane >> 4, cc = lane & 15;
    int kbase = kt*32 + qq*8;
    int col = nt*16 + cc;
    unsigned short tmp[8];
    #pragma unroll
    for(int j=0;j<8;j++) tmp[j] = f2b(W[(size_t)(kbase+j)*HD + col]);
    uint4 o;
    o.x = tmp[0]|((unsigned)tmp[1]<<16); o.y = tmp[2]|((unsigned)tmp[3]<<16);
    o.z = tmp[4]|((unsigned)tmp[5]<<16); o.w = tmp[6]|((unsigned)tmp[7]<<16);
    *(uint4*)&Wb[(size_t)idx*8] = o;
    return;
  }
  if(b == 24){
    // ---- per-graph node counts ----
    int g = threadIdx.x;
    if(g >= NG) return;
    int lo=0, hi=N;
    while(lo<hi){ int mid=(lo+hi)>>1; if(gid[mid] < g) lo=mid+1; else hi=mid; }
    int start = lo; lo = start; hi = N;
    while(lo<hi){ int mid=(lo+hi)>>1; if(gid[mid] < g+1) lo=mid+1; else hi=mid; }
    cnt[g] = (float)(lo - start);
    return;
  }
  // ---- hg zero: blocks [25, 49), 3*NG*HD floats ----
  int i = ((b-25)*256 + threadIdx.x)*4;
  *(float4*)&hg[i] = (float4){0.f,0.f,0.f,0.f};
}

__global__ __launch_bounds__(64) void k_bsum(const int* __restrict__ deg, int* __restrict__ bsum, int N){
  int b = blockIdx.x, t = threadIdx.x;
  int i = b*256 + t*4;
  int s = 0;
  if(i+3 < N){ int4 v = *(const int4*)&deg[i]; s = v.x+v.y+v.z+v.w; }
  else { for(int k=0;k<4;k++) if(i+k<N) s += deg[i+k]; }
  #pragma unroll
  for(int o=32;o;o>>=1) s += __shfl_xor(s,o);
  if(t==0) bsum[b] = s;
}

// bprop with inline prefix of bsum (replaces the separate bscan kernel):
// each block sums bsum[0..b) itself (<=196 ints, parallel across lanes).
__global__ __launch_bounds__(256) void k_bprop2(const int* __restrict__ deg,
                                                const int* __restrict__ bsum,
                                                int* __restrict__ offs, int N, int E){
  __shared__ int sh[256];
  __shared__ int sbase;
  int b = blockIdx.x, t = threadIdx.x;
  int s = 0;
  for(int j=t; j<b; j+=256) s += bsum[j];
  #pragma unroll
  for(int o=32;o;o>>=1) s += __shfl_xor(s,o);
  if(t < 4) sh[t] = 0;
  __syncthreads();
  if((t&63)==0) sh[t>>6] = s;
  __syncthreads();
  if(t==0) sbase = sh[0]+sh[1]+sh[2]+sh[3];
  __syncthreads();
  int i = b*256 + t;
  int v = (i<N) ? deg[i] : 0;
  sh[t] = v; __syncthreads();
  for(int o=1;o<256;o<<=1){ int u = (t>=o)?sh[t-o]:0; __syncthreads(); sh[t]+=u; __syncthreads(); }
  if(i<N) offs[i] = sbase + sh[t] - v;
  if(b==0 && t==0) offs[N] = E;
}

// ================= device bodies reused by merged kernels =================

// scatter + fused edge dots (4 lanes/edge, atomic-free via rank)
__device__ __forceinline__ void scatter_dev(int bidx,
                           const int* __restrict__ src, const int* __restrict__ dst,
                           const int* __restrict__ rank,
                           const float* __restrict__ ef,
                           const float* __restrict__ a1e, const float* __restrict__ a2e,
                           const float* __restrict__ a3e,
                           const int* __restrict__ offs, uint2* __restrict__ rec, int E){
  int t = bidx*256 + threadIdx.x;
  int e = t >> 2;
  int sub = t & 3;
  if(e >= E) return;
  float4 f  = *(const float4*)&ef[(size_t)e*ED + sub*4];
  float4 A1 = *(const float4*)&a1e[sub*4];
  float4 A2 = *(const float4*)&a2e[sub*4];
  float4 A3 = *(const float4*)&a3e[sub*4];
  float q1 = fmaf(f.x,A1.x, fmaf(f.y,A1.y, fmaf(f.z,A1.z, f.w*A1.w)));
  float q2 = fmaf(f.x,A2.x, fmaf(f.y,A2.y, fmaf(f.z,A2.z, f.w*A2.w)));
  float q3 = fmaf(f.x,A3.x, fmaf(f.y,A3.y, fmaf(f.z,A3.z, f.w*A3.w)));
  q1 += __shfl_xor(q1,1); q1 += __shfl_xor(q1,2);
  q2 += __shfl_xor(q2,1); q2 += __shfl_xor(q2,2);
  q3 += __shfl_xor(q3,1); q3 += __shfl_xor(q3,2);
  if(sub == 0){
    int d = dst[e];
    int p = offs[d] + rank[e];
    uint2 A;
    A.x = (unsigned)f2b(q1) | ((unsigned)f2b(q2) << 16);
    A.y = (unsigned)src[e] | ((unsigned)f2b(q3) << 16);
    rec[p] = A;
  }
}

// MFMA GEMM tile (one 128-row block) + fused pdots
__device__ __forceinline__ void gemm_dev(int bidx,
    const unsigned short* __restrict__ Ab,
    const unsigned short* __restrict__ Wb,
    unsigned short* __restrict__ Zb,
    const float* __restrict__ avec,
    float* __restrict__ ps, float* __restrict__ pd, int M)
{
  int tid = threadIdx.x;
  int w = tid >> 6, lane = tid & 63;
  int q = lane >> 4, c = lane & 15;
  int rowbase = bidx*128 + w*32;
  f32x4 acc[2][8];
  #pragma unroll
  for(int t=0;t<2;t++)
    #pragma unroll
    for(int n=0;n<8;n++) acc[t][n] = (f32x4){0.f,0.f,0.f,0.f};

  int r0 = rowbase + c;      if(r0 > M-1) r0 = M-1;
  int r1 = rowbase + 16 + c; if(r1 > M-1) r1 = M-1;
  #pragma unroll
  for(int kt=0; kt<4; kt++){
    int ko = kt*32 + q*8;
    bf16x8 a0 = __builtin_bit_cast(bf16x8, *(const uint4*)&Ab[(size_t)r0*HD + ko]);
    bf16x8 a1 = __builtin_bit_cast(bf16x8, *(const uint4*)&Ab[(size_t)r1*HD + ko]);
    #pragma unroll
    for(int n=0;n<8;n++){
      bf16x8 b = __builtin_bit_cast(bf16x8, *(const uint4*)&Wb[(((size_t)(kt*8+n))*64 + lane)*8]);
      acc[0][n] = __builtin_amdgcn_mfma_f32_16x16x32_bf16(a0, b, acc[0][n], 0,0,0);
      acc[1][n] = __builtin_amdgcn_mfma_f32_16x16x32_bf16(a1, b, acc[1][n], 0,0,0);
    }
  }
  float asv[8], adv[8];
  #pragma unroll
  for(int n=0;n<8;n++){ asv[n] = avec[n*16+c]; adv[n] = avec[HD + n*16+c]; }
  #pragma unroll
  for(int t=0;t<2;t++){
    #pragma unroll
    for(int r=0;r<4;r++){
      int grow = rowbase + t*16 + 4*q + r;
      bool ok = grow < M;
      #pragma unroll
      for(int n=0;n<8;n++){
        if(ok) Zb[(size_t)grow*HD + n*16 + c] = f2b(acc[t][n][r]);
      }
      float pp = 0.f, dd = 0.f;
      #pragma unroll
      for(int n=0;n<8;n++){ pp = fmaf(acc[t][n][r], asv[n], pp); dd = fmaf(acc[t][n][r], adv[n], dd); }
      #pragma unroll
      for(int o=1;o<16;o<<=1){ pp += __shfl_xor(pp,o); dd += __shfl_xor(dd,o); }
      if(ok && c==0){ ps[grow] = pp; pd[grow] = dd; }
    }
  }
}

// readout chunk, 256-thread shape: 4 chunks (one per 64-lane group) of one graph
#define RCH 16
__device__ __forceinline__ void readout_dev(int rb,
                          const unsigned* __restrict__ hbu,
                          const float* __restrict__ att,
                          const int* __restrict__ gid,
                          float* __restrict__ hg, int N){
  int g = rb >> 2;
  int chunk = ((rb & 3) << 2) + (threadIdx.x >> 6);
  int t = threadIdx.x & 63;
  int lo=0, hi=N;
  while(lo<hi){ int mid=(lo+hi)>>1; if(gid[mid] < g) lo=mid+1; else hi=mid; }
  int start = lo; lo = start; hi = N;
  while(lo<hi){ int mid=(lo+hi)>>1; if(gid[mid] < g+1) lo=mid+1; else hi=mid; }
  int end = lo;
  int len = end - start;
  int c0 = start + (int)(((long long)len * chunk) / RCH);
  int c1 = start + (int)(((long long)len * (chunk+1)) / RCH);
  float acc0 = 0.f, acc1 = 0.f;
  for(int v=c0; v<c1; v++){
    unsigned P = hbu[(size_t)v*64 + t];
    float a = att[v];
    acc0 = fmaf(a, blo(P), acc0);
    acc1 = fmaf(a, bhi(P), acc1);
  }
  atomicAdd(&hg[g*HD + 2*t],     acc0);
  atomicAdd(&hg[g*HD + 2*t + 1], acc1);
}

// ================= merged dispatches =================
// scatterq ∥ gemm(layer1): both depend only on {bprop2, k_pre}
__global__ __launch_bounds__(256) void k_sg1(
    const unsigned short* __restrict__ Ab, const unsigned short* __restrict__ Wb,
    unsigned short* __restrict__ Zb, const float* __restrict__ avec,
    float* __restrict__ ps, float* __restrict__ pd, int M, int GB,
    const int* __restrict__ src, const int* __restrict__ dst, const int* __restrict__ rank,
    const float* __restrict__ ef, const float* __restrict__ a1e, const float* __restrict__ a2e,
    const float* __restrict__ a3e, const int* __restrict__ offs, uint2* __restrict__ rec, int E){
  if(blockIdx.x < GB) gemm_dev(blockIdx.x, Ab, Wb, Zb, avec, ps, pd, M);
  else scatter_dev(blockIdx.x - GB, src, dst, rank, ef, a1e, a2e, a3e, offs, rec, E);
}

// readout(L) ∥ gemm(L+1): both depend only on agg2(L)
__global__ __launch_bounds__(256) void k_rg(
    const unsigned short* __restrict__ Ab, const unsigned short* __restrict__ Wb,
    unsigned short* __restrict__ Zb, const float* __restrict__ avec,
    float* __restrict__ ps, float* __restrict__ pd, int M, int GB,
    const unsigned* __restrict__ hbu, const float* __restrict__ att,
    const int* __restrict__ gid, float* __restrict__ hg, int N){
  if(blockIdx.x < GB) gemm_dev(blockIdx.x, Ab, Wb, Zb, avec, ps, pd, M);
  else readout_dev(blockIdx.x - GB, hbu, att, gid, hg, N);
}

// ---------------- fused logits + softmax + aggregate + relu + h(bf16) + att ----------------
// PROVEN 43us structure (R2): phase 1 per-lane weights, phase 2 16-edge groups.
__global__ __launch_bounds__(256) void k_agg2(const uint4* __restrict__ zb4,
                                              const int* __restrict__ offs,
                                              const uint2* __restrict__ rec,
                                              const float* __restrict__ ps,
                                              const float* __restrict__ pd,
                                              int layer,
                                              unsigned* __restrict__ hbu,
                                              float* __restrict__ att,
                                              const float* __restrict__ watt,
                                              const float* __restrict__ batt, int N){
  int wid = blockIdx.x*4 + (threadIdx.x>>6);
  int lane = threadIdx.x & 63;
  if(wid >= N) return;
  int q = lane >> 4, c = lane & 15;
  int d0 = offs[wid], d1 = offs[wid+1];
  float pdv = pd[wid];
  float acc[8];
  #pragma unroll
  for(int i=0;i<8;i++) acc[i]=0.f;
  float ssum = 0.f;

  for(int t0=d0; t0<d1; t0+=64){
    int rem = d1 - t0; if(rem > 64) rem = 64;
    // ---- phase 1: per-lane edge weight ----
    int j = t0 + lane;
    float w = 0.f; int u = 0;
    if(j < d1){
      uint2 R = rec[j];
      u = (int)(R.y & 0xffffu);
      unsigned qb = (layer==0) ? (R.x & 0xffffu) : (layer==1 ? (R.x >> 16) : (R.y >> 16));
      float ql = __uint_as_float(qb << 16);
      float l = ps[u] + pdv + ql;
      l = (l >= 0.f) ? l : 0.2f*l;
      w = __expf(l);
    }
    float ws = w;
    #pragma unroll
    for(int o=32;o;o>>=1) ws += __shfl_xor(ws,o);
    ssum += ws;
    // ---- phase 2: 16 edges per iteration (lanes beyond rem have w=0 -> no guard) ----
    for(int jb=0; jb<rem; jb+=16){
      float w0 = bperm_f(jb+q,    w);  int u0 = bperm_i(jb+q,    u);
      float w1 = bperm_f(jb+4+q,  w);  int u1 = bperm_i(jb+4+q,  u);
      float w2 = bperm_f(jb+8+q,  w);  int u2 = bperm_i(jb+8+q,  u);
      float w3 = bperm_f(jb+12+q, w);  int u3 = bperm_i(jb+12+q, u);
      uint4 P0 = zb4[(size_t)u0*16 + c];
      uint4 P1 = zb4[(size_t)u1*16 + c];
      uint4 P2 = zb4[(size_t)u2*16 + c];
      uint4 P3 = zb4[(size_t)u3*16 + c];
      acc[0] = fmaf(w0, blo(P0.x), acc[0]); acc[1] = fmaf(w0, bhi(P0.x), acc[1]);
      acc[2] = fmaf(w0, blo(P0.y), acc[2]); acc[3] = fmaf(w0, bhi(P0.y), acc[3]);
      acc[4] = fmaf(w0, blo(P0.z), acc[4]); acc[5] = fmaf(w0, bhi(P0.z), acc[5]);
      acc[6] = fmaf(w0, blo(P0.w), acc[6]); acc[7] = fmaf(w0, bhi(P0.w), acc[7]);
      acc[0] = fmaf(w1, blo(P1.x), acc[0]); acc[1] = fmaf(w1, bhi(P1.x), acc[1]);
      acc[2] = fmaf(w1, blo(P1.y), acc[2]); acc[3] = fmaf(w1, bhi(P1.y), acc[3]);
      acc[4] = fmaf(w1, blo(P1.z), acc[4]); acc[5] = fmaf(w1, bhi(P1.z), acc[5]);
      acc[6] = fmaf(w1, blo(P1.w), acc[6]); acc[7] = fmaf(w1, bhi(P1.w), acc[7]);
      acc[0] = fmaf(w2, blo(P2.x), acc[0]); acc[1] = fmaf(w2, bhi(P2.x), acc[1]);
      acc[2] = fmaf(w2, blo(P2.y), acc[2]); acc[3] = fmaf(w2, bhi(P2.y), acc[3]);
      acc[4] = fmaf(w2, blo(P2.z), acc[4]); acc[5] = fmaf(w2, bhi(P2.z), acc[5]);
      acc[6] = fmaf(w2, blo(P2.w), acc[6]); acc[7] = fmaf(w2, bhi(P2.w), acc[7]);
      acc[0] = fmaf(w3, blo(P3.x), acc[0]); acc[1] = fmaf(w3, bhi(P3.x), acc[1]);
      acc[2] = fmaf(w3, blo(P3.y), acc[2]); acc[3] = fmaf(w3, bhi(P3.y), acc[3]);
      acc[4] = fmaf(w3, blo(P3.z), acc[4]); acc[5] = fmaf(w3, bhi(P3.z), acc[5]);
      acc[6] = fmaf(w3, blo(P3.w), acc[6]); acc[7] = fmaf(w3, bhi(P3.w), acc[7]);
    }
  }
  #pragma unroll
  for(int i=0;i<8;i++){ acc[i] += __shfl_xor(acc[i],16); acc[i] += __shfl_xor(acc[i],32); }
  float inv = (d1 > d0) ? 1.0f/ssum : 0.0f;
  #pragma unroll
  for(int i=0;i<8;i++) acc[i] = fmaxf(acc[i]*inv, 0.f);
  hbu[(size_t)wid*64 + c*4 + q] = (unsigned)f2b(acc[2*q]) | ((unsigned)f2b(acc[2*q+1])<<16);
  float4 w0v = *(const float4*)&watt[c*8];
  float4 w1v = *(const float4*)&watt[c*8+4];
  float t = acc[0]*w0v.x + acc[1]*w0v.y + acc[2]*w0v.z + acc[3]*w0v.w
          + acc[4]*w1v.x + acc[5]*w1v.y + acc[6]*w1v.z + acc[7]*w1v.w;
  #pragma unroll
  for(int o=1;o<16;o<<=1) t += __shfl_xor(t,o);
  t += batt[0];
  float lr = (t >= 0.f) ? t : 0.01f*t;
  if(lane==0) att[wid] = __expf(lr);
}

// ---------------- standalone readout for layer 3 ----------------
__global__ __launch_bounds__(64) void k_readout(const unsigned* __restrict__ hbu,
                                                const float* __restrict__ att,
                                                const int* __restrict__ gid,
                                                float* __restrict__ hg, int N){
  int g = blockIdx.x / RCH;
  int chunk = blockIdx.x % RCH;
  int t = threadIdx.x;
  int lo=0, hi=N;
  while(lo<hi){ int mid=(lo+hi)>>1; if(gid[mid] < g) lo=mid+1; else hi=mid; }
  int start = lo; lo = start; hi = N;
  while(lo<hi){ int mid=(lo+hi)>>1; if(gid[mid] < g+1) lo=mid+1; else hi=mid; }
  int end = lo;
  int len = end - start;
  int c0 = start + (int)(((long long)len * chunk) / RCH);
  int c1 = start + (int)(((long long)len * (chunk+1)) / RCH);
  float acc0 = 0.f, acc1 = 0.f;
  for(int v=c0; v<c1; v++){
    unsigned P = hbu[(size_t)v*64 + t];
    float a = att[v];
    acc0 = fmaf(a, blo(P), acc0);
    acc1 = fmaf(a, bhi(P), acc1);
  }
  atomicAdd(&hg[g*HD + 2*t],     acc0);
  atomicAdd(&hg[g*HD + 2*t + 1], acc1);
}

// ---------------- final classifier + log_softmax (block per graph) ----------------
__global__ __launch_bounds__(384) void k_final(const float* __restrict__ hg,
                                               const float* __restrict__ cnt,
                                               const float* __restrict__ Wc,
                                               const float* __restrict__ bc,
                                               float* __restrict__ out){
  int g = blockIdx.x;
  int t = threadIdx.x;
  __shared__ float red[6];
  __shared__ float yv[NC];
  float invc = 1.f / fmaxf(cnt[g], 1.f);
  int part = t >> 7;
  int f = t & 127;
  float v = hg[(size_t)part*NG*HD + g*HD + f] * invc;
  for(int c=0; c<NC; c++){
    float p = v * Wc[(size_t)t*NC + c];
    #pragma unroll
    for(int o=32;o;o>>=1) p += __shfl_xor(p,o);
    if((t&63)==0) red[t>>6] = p;
    __syncthreads();
    if(t==0) yv[c] = bc[c] + red[0]+red[1]+red[2]+red[3]+red[4]+red[5];
    __syncthreads();
  }
  if(t==0){
    float mx = -INFINITY;
    #pragma unroll
    for(int c=0;c<NC;c++) mx = fmaxf(mx, yv[c]);
    float s = 0.f;
    #pragma unroll
    for(int c=0;c<NC;c++) s += __expf(yv[c] - mx);
    float ls = logf(s);
    #pragma unroll
    for(int c=0;c<NC;c++) out[g*NC + c] = yv[c] - mx - ls;
  }
}

// ---------------- host ----------------
extern "C" void kernel_launch(void* const* d_in, const int* in_sizes, int n_in,
                              void* d_out, int out_size, void* d_ws, size_t ws_size,
                              hipStream_t stream) {
  const float* x     = (const float*)d_in[0];
  const float* efeat = (const float*)d_in[1];
  const int*   src   = (const int*)d_in[2];
  const int*   dst   = (const int*)d_in[3];
  const int*   gid   = (const int*)d_in[4];
  const float* W1    = (const float*)d_in[5];
  const float* a1    = (const float*)d_in[6];
  const float* W2    = (const float*)d_in[7];
  const float* a2    = (const float*)d_in[8];
  const float* W3    = (const float*)d_in[9];
  const float* a3    = (const float*)d_in[10];
  const float* watt  = (const float*)d_in[11];
  const float* batt  = (const float*)d_in[12];
  const float* Wc    = (const float*)d_in[13];
  const float* bc    = (const float*)d_in[14];
  float* out = (float*)d_out;

  int N = in_sizes[4];
  int E = in_sizes[2];

  char* p = (char*)d_ws;
  auto alloc = [&](size_t bytes)->void*{
    void* r = (void*)p;
    p += (bytes + 255) & ~(size_t)255;
    return r;
  };
  unsigned short* Xb = (unsigned short*)alloc((size_t)N*HD*2);
  unsigned short* Hb = (unsigned short*)alloc((size_t)N*HD*2);
  unsigned short* Zb = (unsigned short*)alloc((size_t)N*HD*2);
  unsigned short* Wball = (unsigned short*)alloc((size_t)3*2048*8*2);
  float* ps      = (float*)alloc((size_t)N*4);
  float* pd      = (float*)alloc((size_t)N*4);
  float* att     = (float*)alloc((size_t)N*4);
  int*   deg     = (int*)  alloc((size_t)N*4);
  int*   offs    = (int*)  alloc((size_t)(N+1)*4);
  int*   rank    = (int*)  alloc((size_t)E*4);
  uint2* rec     = (uint2*)alloc((size_t)E*8);
  int*   bsum    = (int*)  alloc((size_t)1024*4);
  float* hg      = (float*)alloc((size_t)3*NG*HD*4);
  float* cnt     = (float*)alloc((size_t)NG*4);
  (void)ws_size; (void)n_in; (void)out_size;

  int nwblocks = (N + 3) / 4;
  int nb = (N + 255) / 256;
  int ncast = (N*16 + 255) / 256;
  int NH = (E/4 + 255) / 256;
  int GB = (N + 127) / 128;
  int SB = (E*4 + 255) / 256;

  hipMemsetAsync(deg, 0, (size_t)N*4, stream);
  k_pre<<<NH + ncast + 49, 256, 0, stream>>>(dst, deg, rank, E, NH,
                                             x, Xb, W1, W2, W3, Wball,
                                             gid, cnt, hg, N, ncast);
  k_bsum<<<nb, 64, 0, stream>>>(deg, bsum, N);
  k_bprop2<<<nb, 256, 0, stream>>>(deg, bsum, offs, N, E);
  // scatterq ∥ gemm layer 1
  k_sg1<<<GB + SB, 256, 0, stream>>>(Xb, Wball, Zb, a1, ps, pd, N, GB,
                                     src, dst, rank, efeat,
                                     a1+2*HD, a2+2*HD, a3+2*HD, offs, rec, E);
  k_agg2<<<nwblocks, 256, 0, stream>>>((const uint4*)Zb, offs, rec, ps, pd, 0,
                                       (unsigned*)Hb, att, watt, batt, N);
  // readout L1 ∥ gemm L2
  k_rg<<<GB + NG*4, 256, 0, stream>>>(Hb, Wball + (size_t)1*2048*8, Zb, a2, ps, pd, N, GB,
                                      (const unsigned*)Hb, att, gid, hg + 0*NG*HD, N);
  k_agg2<<<nwblocks, 256, 0, stream>>>((const uint4*)Zb, offs, rec, ps, pd, 1,
                                       (unsigned*)Hb, att, watt, batt, N);
  // readout L2 ∥ gemm L3
  k_rg<<<GB + NG*4, 256, 0, stream>>>(Hb, Wball + (size_t)2*2048*8, Zb, a3, ps, pd, N, GB,
                                      (const unsigned*)Hb, att, gid, hg + 1*NG*HD, N);
  k_agg2<<<nwblocks, 256, 0, stream>>>((const uint4*)Zb, offs, rec, ps, pd, 2,
                                       (unsigned*)Hb, att, watt, batt, N);
  k_readout<<<NG*RCH, 64, 0, stream>>>((const unsigned*)Hb, att, gid,
                                       hg + 2*NG*HD, N);
  k_final<<<NG, 384, 0, stream>>>(hg, cnt, Wc, bc, out);
}